// Round 10
// baseline (419.799 us; speedup 1.0000x reference)
//
#include <hip/hip_runtime.h>
#include <cstdint>
#include <cstddef>

#define NGRAPHS 512

static inline size_t align_up(size_t x, size_t a){ return (x + a - 1) & ~(a - 1); }

// ---------------- bf16 helpers ----------------
__device__ __forceinline__ unsigned short f2bf(float f){
  unsigned int u = __float_as_uint(f);
  u += 0x7FFFu + ((u >> 16) & 1u);          // round-to-nearest-even
  return (unsigned short)(u >> 16);
}
__device__ __forceinline__ float bflo(unsigned int u){ return __uint_as_float(u << 16); }
__device__ __forceinline__ float bfhi(unsigned int u){ return __uint_as_float(u & 0xffff0000u); }
__device__ __forceinline__ unsigned int pack2(float a, float b){
  return (unsigned)f2bf(a) | ((unsigned)f2bf(b) << 16);
}

typedef __attribute__((ext_vector_type(8))) short bf16x8;
typedef __attribute__((ext_vector_type(4))) float f32x4;

// ================= deterministic radix partition (src + dst, LDS histograms only) =================
// blocks >= NBLK handle independent prep work (weight transpose, graph bounds)
__global__ __launch_bounds__(256) void k_partcount(const int* __restrict__ src, const int* __restrict__ dst,
                                                   int* __restrict__ cntS, int* __restrict__ cntD, int n_edges, int NBLK,
                                                   const float* __restrict__ W1, unsigned short* __restrict__ Wt1,
                                                   const float* __restrict__ W2, unsigned short* __restrict__ Wt2,
                                                   const int* __restrict__ gids, int* __restrict__ gb, int n_nodes){
  __shared__ int cs[256], cd[256];
  if (blockIdx.x >= NBLK){
    long long u = (long long)(blockIdx.x - NBLK) * 256 + threadIdx.x;
    if (u < 128 * 256){
      int k = (int)(u / 256), n = (int)(u % 256);
      Wt1[(size_t)n * 128 + k] = f2bf(W1[u]);
      return;
    }
    u -= 128 * 256;
    if (u < 256 * 64){
      int k = (int)(u / 64), n = (int)(u % 64);
      Wt2[(size_t)n * 256 + k] = f2bf(W2[u]);
      return;
    }
    u -= 256 * 64;
    if (u < n_nodes){
      int i = (int)u;
      int g  = gids[i];
      int gp = (i > 0) ? gids[i - 1] : -1;
      for (int q = gp + 1; q <= g; ++q) gb[q] = i;       // sorted ids: gb[q] = first idx with gids >= q
      if (i == n_nodes - 1)
        for (int q = g + 1; q <= NGRAPHS; ++q) gb[q] = n_nodes;
    }
    return;
  }
  int tid = threadIdx.x;
  cs[tid] = 0; cd[tid] = 0;
  __syncthreads();
  int e0 = blockIdx.x * 4096;
  int e1 = min(e0 + 4096, n_edges);
  for (int e = e0 + tid; e < e1; e += 256){
    atomicAdd(&cs[src[e] >> 9], 1);
    atomicAdd(&cd[dst[e] >> 9], 1);
  }
  __syncthreads();
  cntS[blockIdx.x * 256 + tid] = cs[tid];
  cntD[blockIdx.x * 256 + tid] = cd[tid];
}

__global__ __launch_bounds__(256) void k_colscan(int* __restrict__ cntS, int* __restrict__ cntD,
                                                 int* __restrict__ totS, int* __restrict__ totD,
                                                 int nblk, int NB){
  int col = blockIdx.x;
  int* cnt; int* tot; int k;
  if (col < NB){ cnt = cntS; tot = totS; k = col; }
  else         { cnt = cntD; tot = totD; k = col - NB; }
  __shared__ int tsum[256];
  int tid = threadIdx.x;
  int i0 = 2 * tid, i1 = 2 * tid + 1;
  int a = (i0 < nblk) ? cnt[i0 * 256 + k] : 0;
  int b = (i1 < nblk) ? cnt[i1 * 256 + k] : 0;
  int s = a + b;
  tsum[tid] = s;
  __syncthreads();
  for (int off = 1; off < 256; off <<= 1){
    int t = (tid >= off) ? tsum[tid - off] : 0;
    __syncthreads();
    tsum[tid] += t;
    __syncthreads();
  }
  int pre = tsum[tid] - s;
  if (i0 < nblk) cnt[i0 * 256 + k] = pre;
  if (i1 < nblk) cnt[i1 * 256 + k] = pre + a;
  if (tid == 255) tot[k] = tsum[255];
}

// LDS-staged scatter (256 threads): sort block's edges into bucket order in LDS, write coalesced.
__global__ __launch_bounds__(256) void k_scatter_det(const int* __restrict__ src, const int* __restrict__ dst,
                                                     const int* __restrict__ cntS, const int* __restrict__ cntD,
                                                     const int* __restrict__ totS, const int* __restrict__ totD,
                                                     int* __restrict__ baseS, int* __restrict__ baseD,
                                                     int2* __restrict__ pairD, int* __restrict__ srcS,
                                                     int n_edges, int NB){
  __shared__ int s1[256], s2[256];
  __shared__ int gbS[256], gbD[256], lsS[256], lsD[256], lcS[256], lcD[256];
  __shared__ int2 ebuf[4096];
  __shared__ int sbuf[4096];
  int tid = threadIdx.x;
  int b = blockIdx.x;
  // scan totS/totD -> per-bucket global bases
  int v1 = (tid < NB) ? totS[tid] : 0;
  int v2 = (tid < NB) ? totD[tid] : 0;
  s1[tid] = v1; s2[tid] = v2;
  __syncthreads();
  for (int off = 1; off < 256; off <<= 1){
    int t1 = (tid >= off) ? s1[tid - off] : 0;
    int t2 = (tid >= off) ? s2[tid - off] : 0;
    __syncthreads();
    s1[tid] += t1; s2[tid] += t2;
    __syncthreads();
  }
  int bS = s1[tid] - v1, bD = s2[tid] - v2;
  if (b == 0 && tid < NB){ baseS[tid] = bS; baseD[tid] = bD; }
  gbS[tid] = bS + cntS[b * 256 + tid];
  gbD[tid] = bD + cntD[b * 256 + tid];
  __syncthreads();
  int e0 = b * 4096, e1 = min(e0 + 4096, n_edges);
  int ne = e1 - e0;
  // local histograms (reuse s1/s2)
  s1[tid] = 0; s2[tid] = 0;
  __syncthreads();
  for (int e = e0 + tid; e < e1; e += 256){
    atomicAdd(&s1[src[e] >> 9], 1);
    atomicAdd(&s2[dst[e] >> 9], 1);
  }
  __syncthreads();
  int hv1 = s1[tid], hv2 = s2[tid];
  __syncthreads();
  s1[tid] = hv1; s2[tid] = hv2;
  __syncthreads();
  for (int off = 1; off < 256; off <<= 1){
    int t1 = (tid >= off) ? s1[tid - off] : 0;
    int t2 = (tid >= off) ? s2[tid - off] : 0;
    __syncthreads();
    s1[tid] += t1; s2[tid] += t2;
    __syncthreads();
  }
  lsS[tid] = s1[tid] - hv1; lcS[tid] = lsS[tid];
  lsD[tid] = s2[tid] - hv2; lcD[tid] = lsD[tid];
  __syncthreads();
  // LDS scatter into bucket-major order
  for (int e = e0 + tid; e < e1; e += 256){
    int sv = src[e], d = dst[e];
    int lp = atomicAdd(&lcD[d >> 9], 1);
    ebuf[lp] = make_int2(sv, d);
    int sp = atomicAdd(&lcS[sv >> 9], 1);
    sbuf[sp] = sv;
  }
  __syncthreads();
  // coalesced global writes
  for (int i = tid; i < ne; i += 256){
    int2 e = ebuf[i];
    int kd = e.y >> 9;
    pairD[gbD[kd] + i - lsD[kd]] = e;
    int sv = sbuf[i];
    int ks = sv >> 9;
    srcS[gbS[ks] + i - lsS[ks]] = sv;
  }
}

// per-bucket CSR build, split over 2*NB blocks of 256 threads:
//   block b <  NB : dst side — cd histogram -> scan -> offs/din_s -> counting-sort csr fill
//   block b >= NB : src side — cs histogram -> dout_s
__global__ __launch_bounds__(256) void k_bucket_build(const int2* __restrict__ pairD, const int* __restrict__ baseD,
                                                      const int* __restrict__ srcS, const int* __restrict__ baseS,
                                                      int* __restrict__ offs, float* __restrict__ din_s,
                                                      float* __restrict__ dout_s, int* __restrict__ csr_src,
                                                      int NB, int n, int n_edges){
  __shared__ int cnt[512], cur[512];
  __shared__ int tsum[256];
  int tid = threadIdx.x;
  int bb = blockIdx.x;
  bool dstSide = bb < NB;
  int b = dstSide ? bb : bb - NB;
  int node0 = b << 9;
  int nn = min(512, n - node0);
  for (int i = tid; i < 512; i += 256) cnt[i] = 0;
  __syncthreads();
  if (dstSide){
    int jd0 = baseD[b], jd1 = (b + 1 < NB) ? baseD[b + 1] : n_edges;
    for (int j = jd0 + tid; j < jd1; j += 256) atomicAdd(&cnt[pairD[j].y - node0], 1);
    __syncthreads();
    int a0 = cnt[2 * tid], a1 = cnt[2 * tid + 1];
    int s = a0 + a1;
    tsum[tid] = s;
    __syncthreads();
    for (int off = 1; off < 256; off <<= 1){
      int t = (tid >= off) ? tsum[tid - off] : 0;
      __syncthreads();
      tsum[tid] += t;
      __syncthreads();
    }
    int pre = tsum[tid] - s + jd0;
    cur[2 * tid]     = pre;
    cur[2 * tid + 1] = pre + a0;
    __syncthreads();
    for (int i = tid; i < nn; i += 256){
      offs[node0 + i]  = cur[i];
      din_s[node0 + i] = 1.0f / sqrtf((float)max(cnt[i], 1));
    }
    if (b == NB - 1 && tid == 0) offs[n] = n_edges;
    __syncthreads();
    for (int j = jd0 + tid; j < jd1; j += 256){
      int2 e = pairD[j];
      int p = atomicAdd(&cur[e.y - node0], 1);
      csr_src[p] = e.x;
    }
  } else {
    int js0 = baseS[b], js1 = (b + 1 < NB) ? baseS[b + 1] : n_edges;
    for (int j = js0 + tid; j < js1; j += 256) atomicAdd(&cnt[srcS[j] - node0], 1);
    __syncthreads();
    for (int i = tid; i < nn; i += 256)
      dout_s[node0 + i] = 1.0f / sqrtf((float)max(cnt[i], 1));
  }
}

// ---------------- x -> bf16 with dout^-1/2 prescale (full grid, runs after bucket_build) ----------
__global__ __launch_bounds__(256) void k_prep2(const float* __restrict__ x,
                                               const float* __restrict__ dout_s,
                                               unsigned int* __restrict__ xb, long long total4){
  long long t = (long long)blockIdx.x * 256 + threadIdx.x;
  if (t >= total4) return;
  float4 v = ((const float4*)x)[t];
  float s = dout_s[t >> 5];
  xb[t * 2 + 0] = pack2(v.x * s, v.y * s);
  xb[t * 2 + 1] = pack2(v.z * s, v.w * s);
}

// ---------------- gather helpers ----------------
__device__ __forceinline__ void gath4(const unsigned int* __restrict__ xb, const int* __restrict__ cs,
                                      int j, int lane, float &ax, float &ay){
  int s0 = cs[j], s1 = cs[j + 1], s2 = cs[j + 2], s3 = cs[j + 3];
  unsigned v0 = xb[(size_t)s0 * 64 + lane];
  unsigned v1 = xb[(size_t)s1 * 64 + lane];
  unsigned v2 = xb[(size_t)s2 * 64 + lane];
  unsigned v3 = xb[(size_t)s3 * 64 + lane];
  ax += bflo(v0) + bflo(v1) + bflo(v2) + bflo(v3);
  ay += bfhi(v0) + bfhi(v1) + bfhi(v2) + bfhi(v3);
}

// ======= fused SpMM1 + double-GEMM: t2 = (relu(din*((A x)@W1)+b1)*dout) @ W2 =======
// Zero barriers: each wave owns 32 rows end-to-end (gather -> As -> GEMM1 -> Hs -> GEMM2 -> T2).
// Wt1/Wt2 fragments load straight from global (L2-hot, wave-uniform broadcast) -> no Bs tile.
__global__ __launch_bounds__(256) void k_spmmgemm(const unsigned int* __restrict__ xb,
    const int* __restrict__ offs, const int* __restrict__ csr_src,
    const unsigned short* __restrict__ Wt1, const unsigned short* __restrict__ Wt2,
    unsigned short* __restrict__ T2,
    int M, const float* __restrict__ din, const float* __restrict__ dout,
    const float* __restrict__ bias){
  constexpr int LDA = 136;   // shorts; 272B row stride -> 2-way (free) bank aliasing
  constexpr int LDH = 72;    // shorts; 144B row stride -> 2-way aliasing
  __shared__ __align__(16) unsigned short As[128 * LDA];
  __shared__ __align__(16) unsigned short Hs[128 * LDH];
  int tid = threadIdx.x;
  int bm0 = blockIdx.x * 128;
  int wid = tid >> 6, lane = tid & 63;
  int wm = wid * 32;
  int quad = lane >> 4, l16 = lane & 15;

  // ---- phase 1: gather this wave's 32 rows into As (bf16), two nodes in flight ----
  unsigned int* Asw = (unsigned int*)As;          // row m starts at uint index m*(LDA/2)
  for (int i = 0; i < 16; ++i){
    int mA = wm + 2 * i, mB = mA + 1;
    int gA = bm0 + mA, gB = bm0 + mB;
    float axA = 0.f, ayA = 0.f, axB = 0.f, ayB = 0.f;
    if (gB < M){
      int ja = offs[gA], ja1 = offs[gA + 1];
      int jb = offs[gB], jb1 = offs[gB + 1];
      for (; ja + 4 <= ja1 && jb + 4 <= jb1; ja += 4, jb += 4){
        gath4(xb, csr_src, ja, lane, axA, ayA);
        gath4(xb, csr_src, jb, lane, axB, ayB);
      }
      for (; ja + 4 <= ja1; ja += 4) gath4(xb, csr_src, ja, lane, axA, ayA);
      for (; ja < ja1; ++ja){
        unsigned v = xb[(size_t)csr_src[ja] * 64 + lane];
        axA += bflo(v); ayA += bfhi(v);
      }
      for (; jb + 4 <= jb1; jb += 4) gath4(xb, csr_src, jb, lane, axB, ayB);
      for (; jb < jb1; ++jb){
        unsigned v = xb[(size_t)csr_src[jb] * 64 + lane];
        axB += bflo(v); ayB += bfhi(v);
      }
    } else if (gA < M){
      int ja = offs[gA], ja1 = offs[gA + 1];
      for (; ja + 8 <= ja1; ja += 8){
        gath4(xb, csr_src, ja, lane, axA, ayA);
        gath4(xb, csr_src, ja + 4, lane, axB, ayB);   // second acc pair for ILP
      }
      for (; ja + 4 <= ja1; ja += 4) gath4(xb, csr_src, ja, lane, axA, ayA);
      for (; ja < ja1; ++ja){
        unsigned v = xb[(size_t)csr_src[ja] * 64 + lane];
        axA += bflo(v); ayA += bfhi(v);
      }
      axA += axB; ayA += ayB; axB = 0.f; ayB = 0.f;
    }
    Asw[(size_t)mA * (LDA / 2) + lane] = pack2(axA, ayA);
    Asw[(size_t)mB * (LDA / 2) + lane] = pack2(axB, ayB);
  }

  // ---- phase 2: per-row epilogue scales, then GEMM1 -> Hs -> GEMM2 (own rows only) ----
  float rsv[2][4], rs2v[2][4];
#pragma unroll
  for (int t = 0; t < 2; ++t)
#pragma unroll
    for (int r = 0; r < 4; ++r){
      int gr = bm0 + wm + t * 16 + quad * 4 + r;
      rsv[t][r]  = (gr < M) ? din[gr]  : 0.f;
      rs2v[t][r] = (gr < M) ? dout[gr] : 0.f;
    }
  f32x4 tacc[2][4];
#pragma unroll
  for (int t = 0; t < 2; ++t)
#pragma unroll
    for (int u = 0; u < 4; ++u) tacc[t][u] = f32x4{0.f, 0.f, 0.f, 0.f};

  for (int nt = 0; nt < 4; ++nt){
    // ---- h1 chunk (32 rows x 64 cols per wave) = As @ Wt1_chunk^T ----
    f32x4 acc[2][4];
#pragma unroll
    for (int t = 0; t < 2; ++t)
#pragma unroll
      for (int u = 0; u < 4; ++u) acc[t][u] = f32x4{0.f, 0.f, 0.f, 0.f};
#pragma unroll
    for (int ks = 0; ks < 4; ++ks){
      bf16x8 af[2], bfr[4];
#pragma unroll
      for (int t = 0; t < 2; ++t)
        af[t] = *(const bf16x8*)&As[(wm + t * 16 + l16) * LDA + ks * 32 + quad * 8];
#pragma unroll
      for (int u = 0; u < 4; ++u)
        bfr[u] = *(const bf16x8*)(Wt1 + (size_t)(nt * 64 + u * 16 + l16) * 128 + ks * 32 + quad * 8);
#pragma unroll
      for (int t = 0; t < 2; ++t)
#pragma unroll
        for (int u = 0; u < 4; ++u)
          acc[t][u] = __builtin_amdgcn_mfma_f32_16x16x32_bf16(af[t], bfr[u], acc[t][u], 0, 0, 0);
    }
    // ---- epilogue: relu(din*acc + b1)*dout -> bf16 Hs (own rows) ----
    float bv[4];
#pragma unroll
    for (int u = 0; u < 4; ++u) bv[u] = bias[nt * 64 + u * 16 + l16];
#pragma unroll
    for (int t = 0; t < 2; ++t)
#pragma unroll
      for (int r = 0; r < 4; ++r){
        int row = wm + t * 16 + quad * 4 + r;
#pragma unroll
        for (int u = 0; u < 4; ++u){
          float cv = fmaxf(fmaf(acc[t][u][r], rsv[t][r], bv[u]), 0.f) * rs2v[t][r];
          Hs[row * LDH + u * 16 + l16] = f2bf(cv);
        }
      }
    // ---- t2 += h1_chunk @ W2_chunk (Wt2 from global, L2-hot) ----
#pragma unroll
    for (int ks2 = 0; ks2 < 2; ++ks2){
      bf16x8 haf[2], wbf[4];
#pragma unroll
      for (int t = 0; t < 2; ++t)
        haf[t] = *(const bf16x8*)&Hs[(wm + t * 16 + l16) * LDH + ks2 * 32 + quad * 8];
#pragma unroll
      for (int u = 0; u < 4; ++u)
        wbf[u] = *(const bf16x8*)(Wt2 + (size_t)(u * 16 + l16) * 256 + nt * 64 + ks2 * 32 + quad * 8);
#pragma unroll
      for (int t = 0; t < 2; ++t)
#pragma unroll
        for (int u = 0; u < 4; ++u)
          tacc[t][u] = __builtin_amdgcn_mfma_f32_16x16x32_bf16(haf[t], wbf[u], tacc[t][u], 0, 0, 0);
    }
  }
  // ---- write t2 (bf16) ----
#pragma unroll
  for (int t = 0; t < 2; ++t)
#pragma unroll
    for (int r = 0; r < 4; ++r){
      int gr = bm0 + wm + t * 16 + quad * 4 + r;
      if (gr < M){
#pragma unroll
        for (int u = 0; u < 4; ++u)
          T2[(size_t)gr * 64 + u * 16 + l16] = f2bf(tacc[t][u][r]);
      }
    }
}

// ---------------- fused SpMM layer2 + per-graph mean-pool sums: one node per wave, 8 edges/iter ----
#define SCHUNK 4
__global__ __launch_bounds__(256) void k_spmm2_fused(const unsigned short* __restrict__ t2,
    const int* __restrict__ offs, const int* __restrict__ csr_src,
    const float* __restrict__ din_s, const float* __restrict__ b2,
    const int* __restrict__ gb, float* __restrict__ sums){
  __shared__ float bs[64];
  int tid = threadIdx.x;
  int g = blockIdx.x & (NGRAPHS - 1);
  int chunk = blockIdx.x >> 9;
  int wW = __builtin_amdgcn_readfirstlane(chunk * 4 + (tid >> 6));   // wave index in graph [0,16)
  int lane = tid & 63, half = lane >> 5, l = lane & 31;
  if (tid < 64) bs[tid] = 0.f;
  __syncthreads();
  int g0 = gb[g], g1 = gb[g + 1];
  const unsigned int* tp = (const unsigned int*)t2;
  float2 bb = ((const float2*)b2)[l];
  float gxs = 0.f, gys = 0.f;
  for (int node = g0 + wW; node < g1; node += 16){
    int j0 = offs[node], j1 = offs[node + 1];
    float ax = 0.f, ay = 0.f;
    int j = j0;
    for (; j + 8 <= j1; j += 8){
      int s0 = csr_src[j + 0];
      int s1 = csr_src[j + 1];
      int s2 = csr_src[j + 2];
      int s3 = csr_src[j + 3];
      int s4 = csr_src[j + 4];
      int s5 = csr_src[j + 5];
      int s6 = csr_src[j + 6];
      int s7 = csr_src[j + 7];
      unsigned va = tp[(size_t)(half ? s1 : s0) * 32 + l];
      unsigned vb = tp[(size_t)(half ? s3 : s2) * 32 + l];
      unsigned vc = tp[(size_t)(half ? s5 : s4) * 32 + l];
      unsigned vd = tp[(size_t)(half ? s7 : s6) * 32 + l];
      ax += bflo(va) + bflo(vb) + bflo(vc) + bflo(vd);
      ay += bfhi(va) + bfhi(vb) + bfhi(vc) + bfhi(vd);
    }
    for (; j + 4 <= j1; j += 4){
      int s0 = csr_src[j + 0];
      int s1 = csr_src[j + 1];
      int s2 = csr_src[j + 2];
      int s3 = csr_src[j + 3];
      unsigned va = tp[(size_t)(half ? s1 : s0) * 32 + l];
      unsigned vb = tp[(size_t)(half ? s3 : s2) * 32 + l];
      ax += bflo(va) + bflo(vb);
      ay += bfhi(va) + bfhi(vb);
    }
    for (; j + 2 <= j1; j += 2){
      int s0 = csr_src[j], s1 = csr_src[j + 1];
      int ss = half ? s1 : s0;
      unsigned v = tp[(size_t)ss * 32 + l];
      ax += bflo(v);
      ay += bfhi(v);
    }
    if (j < j1 && half == 0){
      unsigned v = tp[(size_t)csr_src[j] * 32 + l];
      ax += bflo(v);
      ay += bfhi(v);
    }
    ax += __shfl_xor(ax, 32);
    ay += __shfl_xor(ay, 32);
    float ds = din_s[node];
    gxs += fmaxf(fmaf(ax, ds, bb.x), 0.f);
    gys += fmaxf(fmaf(ay, ds, bb.y), 0.f);
  }
  if (half == 0){
    atomicAdd(&bs[2 * l], gxs);
    atomicAdd(&bs[2 * l + 1], gys);
  }
  __syncthreads();
  if (tid < 64) atomicAdd(&sums[(size_t)g * 64 + tid], bs[tid]);
}

// ---------------- classifier (counts from gb) ----------------
__global__ __launch_bounds__(256) void k_classifier(const float* __restrict__ sums, const int* __restrict__ gb,
    const float* __restrict__ Wc1, const float* __restrict__ bc1,
    const float* __restrict__ Wc2, const float* __restrict__ bc2,
    const float* __restrict__ Wc3, const float* __restrict__ bc3,
    const float* __restrict__ Wc4, const float* __restrict__ bc4,
    float* __restrict__ out){
  __shared__ float w1[64 * 18], w2[18 * 12], w3[12 * 6], w4[6 * 2];
  __shared__ float B1[18], B2[12], B3[6], B4[2];
  int tid = threadIdx.x;
  for (int i = tid; i < 64 * 18; i += 256) w1[i] = Wc1[i];
  for (int i = tid; i < 18 * 12; i += 256) w2[i] = Wc2[i];
  for (int i = tid; i < 12 * 6;  i += 256) w3[i] = Wc3[i];
  for (int i = tid; i < 6 * 2;   i += 256) w4[i] = Wc4[i];
  if (tid < 18) B1[tid] = bc1[tid];
  if (tid < 12) B2[tid] = bc2[tid];
  if (tid < 6)  B3[tid] = bc3[tid];
  if (tid < 2)  B4[tid] = bc4[tid];
  __syncthreads();
  int g = blockIdx.x * 256 + tid;
  float cnt = fmaxf((float)(gb[g + 1] - gb[g]), 1.0f);
  float h[64];
#pragma unroll
  for (int f = 0; f < 64; ++f) h[f] = sums[(size_t)g * 64 + f] / cnt;
  float t1[18];
#pragma unroll
  for (int j = 0; j < 18; ++j){
    float s = B1[j];
    for (int f = 0; f < 64; ++f) s = fmaf(h[f], w1[f * 18 + j], s);
    t1[j] = s;
  }
  float t2[12];
#pragma unroll
  for (int j = 0; j < 12; ++j){
    float s = B2[j];
    for (int f = 0; f < 18; ++f) s = fmaf(t1[f], w2[f * 12 + j], s);
    t2[j] = s;
  }
  float t3[6];
#pragma unroll
  for (int j = 0; j < 6; ++j){
    float s = B3[j];
    for (int f = 0; f < 12; ++f) s = fmaf(t2[f], w3[f * 6 + j], s);
    t3[j] = s;
  }
#pragma unroll
  for (int j = 0; j < 2; ++j){
    float s = B4[j];
    for (int f = 0; f < 6; ++f) s = fmaf(t3[f], w4[f * 2 + j], s);
    out[(size_t)g * 2 + j] = s;
  }
}

extern "C" void kernel_launch(void* const* d_in, const int* in_sizes, int n_in,
                              void* d_out, int out_size, void* d_ws, size_t ws_size,
                              hipStream_t stream){
  const float* x   = (const float*)d_in[0];
  const int*   src = (const int*)d_in[1];
  const int*   dst = (const int*)d_in[2];
  const int*   gid = (const int*)d_in[3];
  const float* W1  = (const float*)d_in[4];
  const float* b1  = (const float*)d_in[5];
  const float* W2  = (const float*)d_in[6];
  const float* b2  = (const float*)d_in[7];
  const float* Wc1 = (const float*)d_in[8];
  const float* bc1 = (const float*)d_in[9];
  const float* Wc2 = (const float*)d_in[10];
  const float* bc2 = (const float*)d_in[11];
  const float* Wc3 = (const float*)d_in[12];
  const float* bc3 = (const float*)d_in[13];
  const float* Wc4 = (const float*)d_in[14];
  const float* bc4 = (const float*)d_in[15];
  float* out = (float*)d_out;

  const int n_nodes = in_sizes[3];
  const int n_edges = in_sizes[1];
  const int F1 = 256, F2 = 64;
  const int NB   = (n_nodes + 511) >> 9;
  const int NBLK = (n_edges + 4095) / 4096;

  char* w = (char*)d_ws;
  size_t o = 0;
  auto alloc = [&](size_t bytes) -> char* {
    char* p = w + o;
    o = align_up(o + bytes, 256);
    return p;
  };
  float* sums      = (float*)alloc((size_t)NGRAPHS * F2 * 4);
  int*   gb        = (int*)  alloc((size_t)(NGRAPHS + 1) * 4);
  int*   cntS      = (int*)  alloc((size_t)NBLK * 256 * 4);
  int*   cntD      = (int*)  alloc((size_t)NBLK * 256 * 4);
  int*   totS      = (int*)  alloc((size_t)256 * 4);
  int*   totD      = (int*)  alloc((size_t)256 * 4);
  int*   baseS     = (int*)  alloc((size_t)256 * 4);
  int*   baseD     = (int*)  alloc((size_t)256 * 4);
  float* dout_s    = (float*)alloc((size_t)n_nodes * 4);
  float* din_s     = (float*)alloc((size_t)n_nodes * 4);
  int*   offs      = (int*)  alloc((size_t)(n_nodes + 1) * 4);
  int*   csr_src   = (int*)  alloc((size_t)n_edges * 4);
  unsigned short* Wt1 = (unsigned short*)alloc((size_t)256 * 128 * 2);
  unsigned short* Wt2 = (unsigned short*)alloc((size_t)64 * 256 * 2);
  unsigned int*   xb  = (unsigned int*)  alloc((size_t)n_nodes * 128 * 2);
  unsigned short* aggb= (unsigned short*)alloc((size_t)n_nodes * 128 * 2);
  unsigned short* h1b = (unsigned short*)alloc((size_t)n_nodes * F1 * 2);
  // aliases inside aggb region (consumed by bucket_build before later stages)
  int2*  pairD = (int2*)aggb;
  int*   srcS  = (int*)((char*)aggb + (size_t)n_edges * 8);
  // t2 lives in the h1b buffer
  unsigned short* t2b = h1b;

  hipMemsetAsync(sums, 0, (size_t)NGRAPHS * F2 * 4, stream);

  // deterministic radix partition + fused CSR build; misc prep rides on partcount's grid
  {
    long long miscTotal = 128 * 256 + 256 * 64 + n_nodes;
    int miscBlocks = (int)((miscTotal + 255) / 256);
    k_partcount<<<NBLK + miscBlocks, 256, 0, stream>>>(src, dst, cntS, cntD, n_edges, NBLK,
                                                       W1, Wt1, W2, Wt2, gid, gb, n_nodes);
  }
  k_colscan     <<<2 * NB, 256, 0, stream>>>(cntS, cntD, totS, totD, NBLK, NB);
  k_scatter_det <<<NBLK, 256, 0, stream>>>(src, dst, cntS, cntD, totS, totD, baseS, baseD, pairD, srcS, n_edges, NB);
  k_bucket_build<<<2 * NB, 256, 0, stream>>>(pairD, baseD, srcS, baseS, offs, din_s, dout_s, csr_src,
                                             NB, n_nodes, n_edges);

  // x -> bf16 prescaled by dout^-1/2 (full grid)
  {
    long long total4 = (long long)n_nodes * 32;
    k_prep2<<<(int)((total4 + 255) / 256), 256, 0, stream>>>(x, dout_s, xb, total4);
  }

  int gx = (n_nodes + 127) / 128;
  // fused layer-1 SpMM + GEMM1 + GEMM2 (aggb and h1 never hit global memory)
  k_spmmgemm<<<gx, 256, 0, stream>>>(xb, offs, csr_src, Wt1, Wt2, t2b,
                                     n_nodes, din_s, dout_s, b1);
  // layer 2 spmm + per-graph mean-pool
  k_spmm2_fused<<<NGRAPHS * SCHUNK, 256, 0, stream>>>(t2b, offs, csr_src, din_s, b2, gb, sums);
  // classifier
  k_classifier<<<NGRAPHS / 256, 256, 0, stream>>>(sums, gb, Wc1, bc1, Wc2, bc2, Wc3, bc3, Wc4, bc4, out);
}

// Round 11
// 320.202 us; speedup vs baseline: 1.3110x; 1.3110x over previous
//
#include <hip/hip_runtime.h>
#include <cstdint>
#include <cstddef>

#define NGRAPHS 512

static inline size_t align_up(size_t x, size_t a){ return (x + a - 1) & ~(a - 1); }

// ---------------- bf16 helpers ----------------
__device__ __forceinline__ unsigned short f2bf(float f){
  unsigned int u = __float_as_uint(f);
  u += 0x7FFFu + ((u >> 16) & 1u);          // round-to-nearest-even
  return (unsigned short)(u >> 16);
}
__device__ __forceinline__ float bflo(unsigned int u){ return __uint_as_float(u << 16); }
__device__ __forceinline__ float bfhi(unsigned int u){ return __uint_as_float(u & 0xffff0000u); }
__device__ __forceinline__ unsigned int pack2(float a, float b){
  return (unsigned)f2bf(a) | ((unsigned)f2bf(b) << 16);
}

typedef __attribute__((ext_vector_type(8))) short bf16x8;
typedef __attribute__((ext_vector_type(4))) float f32x4;

// ================= deterministic radix partition (src + dst, LDS histograms only) =================
// blocks >= NBLK handle independent prep work (weight transpose, graph bounds)
__global__ __launch_bounds__(256) void k_partcount(const int* __restrict__ src, const int* __restrict__ dst,
                                                   int* __restrict__ cntS, int* __restrict__ cntD, int n_edges, int NBLK,
                                                   const float* __restrict__ W1, unsigned short* __restrict__ Wt1,
                                                   const float* __restrict__ W2, unsigned short* __restrict__ Wt2,
                                                   const int* __restrict__ gids, int* __restrict__ gb, int n_nodes){
  __shared__ int cs[256], cd[256];
  if (blockIdx.x >= NBLK){
    long long u = (long long)(blockIdx.x - NBLK) * 256 + threadIdx.x;
    if (u < 128 * 256){
      int k = (int)(u / 256), n = (int)(u % 256);
      Wt1[(size_t)n * 128 + k] = f2bf(W1[u]);
      return;
    }
    u -= 128 * 256;
    if (u < 256 * 64){
      int k = (int)(u / 64), n = (int)(u % 64);
      Wt2[(size_t)n * 256 + k] = f2bf(W2[u]);
      return;
    }
    u -= 256 * 64;
    if (u < n_nodes){
      int i = (int)u;
      int g  = gids[i];
      int gp = (i > 0) ? gids[i - 1] : -1;
      for (int q = gp + 1; q <= g; ++q) gb[q] = i;       // sorted ids: gb[q] = first idx with gids >= q
      if (i == n_nodes - 1)
        for (int q = g + 1; q <= NGRAPHS; ++q) gb[q] = n_nodes;
    }
    return;
  }
  int tid = threadIdx.x;
  cs[tid] = 0; cd[tid] = 0;
  __syncthreads();
  int e0 = blockIdx.x * 4096;
  int e1 = min(e0 + 4096, n_edges);
  for (int e = e0 + tid; e < e1; e += 256){
    atomicAdd(&cs[src[e] >> 9], 1);
    atomicAdd(&cd[dst[e] >> 9], 1);
  }
  __syncthreads();
  cntS[blockIdx.x * 256 + tid] = cs[tid];
  cntD[blockIdx.x * 256 + tid] = cd[tid];
}

__global__ __launch_bounds__(256) void k_colscan(int* __restrict__ cntS, int* __restrict__ cntD,
                                                 int* __restrict__ totS, int* __restrict__ totD,
                                                 int nblk, int NB){
  int col = blockIdx.x;
  int* cnt; int* tot; int k;
  if (col < NB){ cnt = cntS; tot = totS; k = col; }
  else         { cnt = cntD; tot = totD; k = col - NB; }
  __shared__ int tsum[256];
  int tid = threadIdx.x;
  int i0 = 2 * tid, i1 = 2 * tid + 1;
  int a = (i0 < nblk) ? cnt[i0 * 256 + k] : 0;
  int b = (i1 < nblk) ? cnt[i1 * 256 + k] : 0;
  int s = a + b;
  tsum[tid] = s;
  __syncthreads();
  for (int off = 1; off < 256; off <<= 1){
    int t = (tid >= off) ? tsum[tid - off] : 0;
    __syncthreads();
    tsum[tid] += t;
    __syncthreads();
  }
  int pre = tsum[tid] - s;
  if (i0 < nblk) cnt[i0 * 256 + k] = pre;
  if (i1 < nblk) cnt[i1 * 256 + k] = pre + a;
  if (tid == 255) tot[k] = tsum[255];
}

// LDS-staged scatter (256 threads): sort block's edges into bucket order in LDS, write coalesced.
__global__ __launch_bounds__(256) void k_scatter_det(const int* __restrict__ src, const int* __restrict__ dst,
                                                     const int* __restrict__ cntS, const int* __restrict__ cntD,
                                                     const int* __restrict__ totS, const int* __restrict__ totD,
                                                     int* __restrict__ baseS, int* __restrict__ baseD,
                                                     int2* __restrict__ pairD, int* __restrict__ srcS,
                                                     int n_edges, int NB){
  __shared__ int s1[256], s2[256];
  __shared__ int gbS[256], gbD[256], lsS[256], lsD[256], lcS[256], lcD[256];
  __shared__ int2 ebuf[4096];
  __shared__ int sbuf[4096];
  int tid = threadIdx.x;
  int b = blockIdx.x;
  // scan totS/totD -> per-bucket global bases
  int v1 = (tid < NB) ? totS[tid] : 0;
  int v2 = (tid < NB) ? totD[tid] : 0;
  s1[tid] = v1; s2[tid] = v2;
  __syncthreads();
  for (int off = 1; off < 256; off <<= 1){
    int t1 = (tid >= off) ? s1[tid - off] : 0;
    int t2 = (tid >= off) ? s2[tid - off] : 0;
    __syncthreads();
    s1[tid] += t1; s2[tid] += t2;
    __syncthreads();
  }
  int bS = s1[tid] - v1, bD = s2[tid] - v2;
  if (b == 0 && tid < NB){ baseS[tid] = bS; baseD[tid] = bD; }
  gbS[tid] = bS + cntS[b * 256 + tid];
  gbD[tid] = bD + cntD[b * 256 + tid];
  __syncthreads();
  int e0 = b * 4096, e1 = min(e0 + 4096, n_edges);
  int ne = e1 - e0;
  // local histograms (reuse s1/s2)
  s1[tid] = 0; s2[tid] = 0;
  __syncthreads();
  for (int e = e0 + tid; e < e1; e += 256){
    atomicAdd(&s1[src[e] >> 9], 1);
    atomicAdd(&s2[dst[e] >> 9], 1);
  }
  __syncthreads();
  int hv1 = s1[tid], hv2 = s2[tid];
  __syncthreads();
  s1[tid] = hv1; s2[tid] = hv2;
  __syncthreads();
  for (int off = 1; off < 256; off <<= 1){
    int t1 = (tid >= off) ? s1[tid - off] : 0;
    int t2 = (tid >= off) ? s2[tid - off] : 0;
    __syncthreads();
    s1[tid] += t1; s2[tid] += t2;
    __syncthreads();
  }
  lsS[tid] = s1[tid] - hv1; lcS[tid] = lsS[tid];
  lsD[tid] = s2[tid] - hv2; lcD[tid] = lsD[tid];
  __syncthreads();
  // LDS scatter into bucket-major order
  for (int e = e0 + tid; e < e1; e += 256){
    int sv = src[e], d = dst[e];
    int lp = atomicAdd(&lcD[d >> 9], 1);
    ebuf[lp] = make_int2(sv, d);
    int sp = atomicAdd(&lcS[sv >> 9], 1);
    sbuf[sp] = sv;
  }
  __syncthreads();
  // coalesced global writes
  for (int i = tid; i < ne; i += 256){
    int2 e = ebuf[i];
    int kd = e.y >> 9;
    pairD[gbD[kd] + i - lsD[kd]] = e;
    int sv = sbuf[i];
    int ks = sv >> 9;
    srcS[gbS[ks] + i - lsS[ks]] = sv;
  }
}

// per-bucket CSR build, split over 2*NB blocks of 256 threads:
//   block b <  NB : dst side — cd histogram -> scan -> offs/din_s -> counting-sort csr fill
//   block b >= NB : src side — cs histogram -> dout_s
__global__ __launch_bounds__(256) void k_bucket_build(const int2* __restrict__ pairD, const int* __restrict__ baseD,
                                                      const int* __restrict__ srcS, const int* __restrict__ baseS,
                                                      int* __restrict__ offs, float* __restrict__ din_s,
                                                      float* __restrict__ dout_s, int* __restrict__ csr_src,
                                                      int NB, int n, int n_edges){
  __shared__ int cnt[512], cur[512];
  __shared__ int tsum[256];
  int tid = threadIdx.x;
  int bb = blockIdx.x;
  bool dstSide = bb < NB;
  int b = dstSide ? bb : bb - NB;
  int node0 = b << 9;
  int nn = min(512, n - node0);
  for (int i = tid; i < 512; i += 256) cnt[i] = 0;
  __syncthreads();
  if (dstSide){
    int jd0 = baseD[b], jd1 = (b + 1 < NB) ? baseD[b + 1] : n_edges;
    for (int j = jd0 + tid; j < jd1; j += 256) atomicAdd(&cnt[pairD[j].y - node0], 1);
    __syncthreads();
    int a0 = cnt[2 * tid], a1 = cnt[2 * tid + 1];
    int s = a0 + a1;
    tsum[tid] = s;
    __syncthreads();
    for (int off = 1; off < 256; off <<= 1){
      int t = (tid >= off) ? tsum[tid - off] : 0;
      __syncthreads();
      tsum[tid] += t;
      __syncthreads();
    }
    int pre = tsum[tid] - s + jd0;
    cur[2 * tid]     = pre;
    cur[2 * tid + 1] = pre + a0;
    __syncthreads();
    for (int i = tid; i < nn; i += 256){
      offs[node0 + i]  = cur[i];
      din_s[node0 + i] = 1.0f / sqrtf((float)max(cnt[i], 1));
    }
    if (b == NB - 1 && tid == 0) offs[n] = n_edges;
    __syncthreads();
    for (int j = jd0 + tid; j < jd1; j += 256){
      int2 e = pairD[j];
      int p = atomicAdd(&cur[e.y - node0], 1);
      csr_src[p] = e.x;
    }
  } else {
    int js0 = baseS[b], js1 = (b + 1 < NB) ? baseS[b + 1] : n_edges;
    for (int j = js0 + tid; j < js1; j += 256) atomicAdd(&cnt[srcS[j] - node0], 1);
    __syncthreads();
    for (int i = tid; i < nn; i += 256)
      dout_s[node0 + i] = 1.0f / sqrtf((float)max(cnt[i], 1));
  }
}

// ---------------- x -> bf16 with dout^-1/2 prescale (full grid, runs after bucket_build) ----------
__global__ __launch_bounds__(256) void k_prep2(const float* __restrict__ x,
                                               const float* __restrict__ dout_s,
                                               unsigned int* __restrict__ xb, long long total4){
  long long t = (long long)blockIdx.x * 256 + threadIdx.x;
  if (t >= total4) return;
  float4 v = ((const float4*)x)[t];
  float s = dout_s[t >> 5];
  xb[t * 2 + 0] = pack2(v.x * s, v.y * s);
  xb[t * 2 + 1] = pack2(v.z * s, v.w * s);
}

// ---------------- SpMM layer1: one node per wave, scalar indices, 8 gathers in flight ----------
__global__ __launch_bounds__(256) void k_spmm1(const unsigned int* __restrict__ xb,
    const int* __restrict__ offs, const int* __restrict__ csr_src,
    unsigned int* __restrict__ aggb, int n_nodes){
  int node = __builtin_amdgcn_readfirstlane((int)((blockIdx.x * 256u + threadIdx.x) >> 6));
  if (node >= n_nodes) return;
  int lane = threadIdx.x & 63;
  int j0 = offs[node], j1 = offs[node + 1];
  float ax = 0.f, ay = 0.f, bx = 0.f, by = 0.f;
  int j = j0;
  for (; j + 8 <= j1; j += 8){
    int s0 = csr_src[j + 0];
    int s1 = csr_src[j + 1];
    int s2 = csr_src[j + 2];
    int s3 = csr_src[j + 3];
    int s4 = csr_src[j + 4];
    int s5 = csr_src[j + 5];
    int s6 = csr_src[j + 6];
    int s7 = csr_src[j + 7];
    unsigned v0 = xb[(size_t)s0 * 64 + lane];
    unsigned v1 = xb[(size_t)s1 * 64 + lane];
    unsigned v2 = xb[(size_t)s2 * 64 + lane];
    unsigned v3 = xb[(size_t)s3 * 64 + lane];
    unsigned v4 = xb[(size_t)s4 * 64 + lane];
    unsigned v5 = xb[(size_t)s5 * 64 + lane];
    unsigned v6 = xb[(size_t)s6 * 64 + lane];
    unsigned v7 = xb[(size_t)s7 * 64 + lane];
    ax += bflo(v0) + bflo(v1) + bflo(v2) + bflo(v3);
    ay += bfhi(v0) + bfhi(v1) + bfhi(v2) + bfhi(v3);
    bx += bflo(v4) + bflo(v5) + bflo(v6) + bflo(v7);
    by += bfhi(v4) + bfhi(v5) + bfhi(v6) + bfhi(v7);
  }
  for (; j + 4 <= j1; j += 4){
    int s0 = csr_src[j + 0];
    int s1 = csr_src[j + 1];
    int s2 = csr_src[j + 2];
    int s3 = csr_src[j + 3];
    unsigned v0 = xb[(size_t)s0 * 64 + lane];
    unsigned v1 = xb[(size_t)s1 * 64 + lane];
    unsigned v2 = xb[(size_t)s2 * 64 + lane];
    unsigned v3 = xb[(size_t)s3 * 64 + lane];
    ax += bflo(v0) + bflo(v1) + bflo(v2) + bflo(v3);
    ay += bfhi(v0) + bfhi(v1) + bfhi(v2) + bfhi(v3);
  }
  for (; j < j1; ++j){
    unsigned v = xb[(size_t)csr_src[j] * 64 + lane];
    ax += bflo(v);
    ay += bfhi(v);
  }
  ax += bx; ay += by;
  aggb[(size_t)node * 64 + lane] = pack2(ax, ay);
}

// ---------------- fused double-GEMM: t2 = (relu(din*(A@Wt1^T)+b1)*dout) @ W2, h1 never global ----
// A tile (128x128, full K) in LDS; per 64-col chunk of h1: compute in regs, round-trip bf16
// through Hs, then MFMA against Wt2 chunk (register-prefetched) accumulating t2.
__global__ __launch_bounds__(256) void k_gemm12(const unsigned short* __restrict__ A,
    const unsigned short* __restrict__ Bt, const unsigned short* __restrict__ Wt2,
    unsigned short* __restrict__ T2,
    int M, const float* __restrict__ din, const float* __restrict__ dout,
    const float* __restrict__ bias){
  constexpr int LDA = 136;   // shorts; 272B row stride -> 2-way (free) bank aliasing on ds_read_b128
  constexpr int LDH = 72;    // shorts; 144B row stride -> 2-way aliasing on Hs reads
  __shared__ __align__(16) unsigned short As[128 * LDA];
  __shared__ __align__(16) unsigned short Bs[64 * LDA];
  __shared__ __align__(16) unsigned short Hs[128 * LDH];
  int tid = threadIdx.x;
  int bm0 = blockIdx.x * 128;
  int wid = tid >> 6, lane = tid & 63;
  int wm = wid * 32;
  int quad = lane >> 4, l16 = lane & 15;

  uint4 areg[8];
#pragma unroll
  for (int it = 0; it < 8; ++it){
    int i = tid + it * 256;
    int m = i >> 4, c = i & 15;
    int gr = bm0 + m;
    areg[it] = (gr < M) ? *(const uint4*)(A + (size_t)gr * 128 + c * 8) : make_uint4(0u, 0u, 0u, 0u);
  }
  uint4 breg[4];
#pragma unroll
  for (int it = 0; it < 4; ++it){
    int i = tid + it * 256;
    int n = i >> 4, c = i & 15;
    breg[it] = *(const uint4*)(Bt + (size_t)n * 128 + c * 8);
  }
#pragma unroll
  for (int it = 0; it < 8; ++it){
    int i = tid + it * 256;
    int m = i >> 4, c = i & 15;
    *(uint4*)&As[m * LDA + c * 8] = areg[it];
  }
#pragma unroll
  for (int it = 0; it < 4; ++it){
    int i = tid + it * 256;
    int n = i >> 4, c = i & 15;
    *(uint4*)&Bs[n * LDA + c * 8] = breg[it];
  }
  float rsv[2][4], rs2v[2][4];
#pragma unroll
  for (int t = 0; t < 2; ++t)
#pragma unroll
    for (int r = 0; r < 4; ++r){
      int gr = bm0 + wm + t * 16 + quad * 4 + r;
      rsv[t][r]  = (gr < M) ? din[gr]  : 0.f;
      rs2v[t][r] = (gr < M) ? dout[gr] : 0.f;
    }
  f32x4 tacc[2][4];
#pragma unroll
  for (int t = 0; t < 2; ++t)
#pragma unroll
    for (int u = 0; u < 4; ++u) tacc[t][u] = f32x4{0.f, 0.f, 0.f, 0.f};
  __syncthreads();

  for (int nt = 0; nt < 4; ++nt){
    // prefetch Wt2 chunk into registers early (hides global latency behind first GEMM's MFMAs)
    bf16x8 wpre[2][4];
#pragma unroll
    for (int ks2 = 0; ks2 < 2; ++ks2)
#pragma unroll
      for (int u = 0; u < 4; ++u)
        wpre[ks2][u] = *(const bf16x8*)(Wt2 + (size_t)(u * 16 + l16) * 256 + nt * 64 + ks2 * 32 + quad * 8);
    // prefetch next Bt chunk while computing
    if (nt < 3){
#pragma unroll
      for (int it = 0; it < 4; ++it){
        int i = tid + it * 256;
        int n = i >> 4, c = i & 15;
        breg[it] = *(const uint4*)(Bt + (size_t)((nt + 1) * 64 + n) * 128 + c * 8);
      }
    }
    // ---- h1 chunk (128 x 64) = A @ Wt1_chunk^T ----
    f32x4 acc[2][4];
#pragma unroll
    for (int t = 0; t < 2; ++t)
#pragma unroll
      for (int u = 0; u < 4; ++u) acc[t][u] = f32x4{0.f, 0.f, 0.f, 0.f};
#pragma unroll
    for (int ks = 0; ks < 4; ++ks){
      bf16x8 af[2], bfr[4];
#pragma unroll
      for (int t = 0; t < 2; ++t)
        af[t] = *(const bf16x8*)&As[(wm + t * 16 + l16) * LDA + ks * 32 + quad * 8];
#pragma unroll
      for (int u = 0; u < 4; ++u)
        bfr[u] = *(const bf16x8*)&Bs[(u * 16 + l16) * LDA + ks * 32 + quad * 8];
#pragma unroll
      for (int t = 0; t < 2; ++t)
#pragma unroll
        for (int u = 0; u < 4; ++u)
          acc[t][u] = __builtin_amdgcn_mfma_f32_16x16x32_bf16(af[t], bfr[u], acc[t][u], 0, 0, 0);
    }
    // ---- epilogue: relu(din*acc + b1)*dout -> bf16 Hs ----
    float bv[4];
#pragma unroll
    for (int u = 0; u < 4; ++u) bv[u] = bias[nt * 64 + u * 16 + l16];
#pragma unroll
    for (int t = 0; t < 2; ++t)
#pragma unroll
      for (int r = 0; r < 4; ++r){
        int row = wm + t * 16 + quad * 4 + r;
#pragma unroll
        for (int u = 0; u < 4; ++u){
          float cv = fmaxf(fmaf(acc[t][u][r], rsv[t][r], bv[u]), 0.f) * rs2v[t][r];
          Hs[row * LDH + u * 16 + l16] = f2bf(cv);
        }
      }
    __syncthreads();
    // ---- t2 += h1_chunk (128x64) @ W2_chunk (64x64), Wt2 already in registers ----
#pragma unroll
    for (int ks2 = 0; ks2 < 2; ++ks2){
      bf16x8 haf[2];
#pragma unroll
      for (int t = 0; t < 2; ++t)
        haf[t] = *(const bf16x8*)&Hs[(wm + t * 16 + l16) * LDH + ks2 * 32 + quad * 8];
#pragma unroll
      for (int t = 0; t < 2; ++t)
#pragma unroll
        for (int u = 0; u < 4; ++u)
          tacc[t][u] = __builtin_amdgcn_mfma_f32_16x16x32_bf16(haf[t], wpre[ks2][u], tacc[t][u], 0, 0, 0);
    }
    __syncthreads();
    if (nt < 3){
#pragma unroll
      for (int it = 0; it < 4; ++it){
        int i = tid + it * 256;
        int n = i >> 4, c = i & 15;
        *(uint4*)&Bs[n * LDA + c * 8] = breg[it];
      }
      __syncthreads();
    }
  }
  // ---- write t2 (bf16, 128x64 per block) ----
#pragma unroll
  for (int t = 0; t < 2; ++t)
#pragma unroll
    for (int r = 0; r < 4; ++r){
      int gr = bm0 + wm + t * 16 + quad * 4 + r;
      if (gr < M){
#pragma unroll
        for (int u = 0; u < 4; ++u)
          T2[(size_t)gr * 64 + u * 16 + l16] = f2bf(tacc[t][u][r]);
      }
    }
}

// ---------------- fused SpMM layer2 + per-graph mean-pool sums: one node per wave, 8 edges/iter ----
#define SCHUNK 4
__global__ __launch_bounds__(256) void k_spmm2_fused(const unsigned short* __restrict__ t2,
    const int* __restrict__ offs, const int* __restrict__ csr_src,
    const float* __restrict__ din_s, const float* __restrict__ b2,
    const int* __restrict__ gb, float* __restrict__ sums){
  __shared__ float bs[64];
  int tid = threadIdx.x;
  int g = blockIdx.x & (NGRAPHS - 1);
  int chunk = blockIdx.x >> 9;
  int wW = __builtin_amdgcn_readfirstlane(chunk * 4 + (tid >> 6));   // wave index in graph [0,16)
  int lane = tid & 63, half = lane >> 5, l = lane & 31;
  if (tid < 64) bs[tid] = 0.f;
  __syncthreads();
  int g0 = gb[g], g1 = gb[g + 1];
  const unsigned int* tp = (const unsigned int*)t2;
  float2 bb = ((const float2*)b2)[l];
  float gxs = 0.f, gys = 0.f;
  for (int node = g0 + wW; node < g1; node += 16){
    int j0 = offs[node], j1 = offs[node + 1];
    float ax = 0.f, ay = 0.f;
    int j = j0;
    for (; j + 8 <= j1; j += 8){
      int s0 = csr_src[j + 0];
      int s1 = csr_src[j + 1];
      int s2 = csr_src[j + 2];
      int s3 = csr_src[j + 3];
      int s4 = csr_src[j + 4];
      int s5 = csr_src[j + 5];
      int s6 = csr_src[j + 6];
      int s7 = csr_src[j + 7];
      unsigned va = tp[(size_t)(half ? s1 : s0) * 32 + l];
      unsigned vb = tp[(size_t)(half ? s3 : s2) * 32 + l];
      unsigned vc = tp[(size_t)(half ? s5 : s4) * 32 + l];
      unsigned vd = tp[(size_t)(half ? s7 : s6) * 32 + l];
      ax += bflo(va) + bflo(vb) + bflo(vc) + bflo(vd);
      ay += bfhi(va) + bfhi(vb) + bfhi(vc) + bfhi(vd);
    }
    for (; j + 4 <= j1; j += 4){
      int s0 = csr_src[j + 0];
      int s1 = csr_src[j + 1];
      int s2 = csr_src[j + 2];
      int s3 = csr_src[j + 3];
      unsigned va = tp[(size_t)(half ? s1 : s0) * 32 + l];
      unsigned vb = tp[(size_t)(half ? s3 : s2) * 32 + l];
      ax += bflo(va) + bflo(vb);
      ay += bfhi(va) + bfhi(vb);
    }
    for (; j + 2 <= j1; j += 2){
      int s0 = csr_src[j], s1 = csr_src[j + 1];
      int ss = half ? s1 : s0;
      unsigned v = tp[(size_t)ss * 32 + l];
      ax += bflo(v);
      ay += bfhi(v);
    }
    if (j < j1 && half == 0){
      unsigned v = tp[(size_t)csr_src[j] * 32 + l];
      ax += bflo(v);
      ay += bfhi(v);
    }
    ax += __shfl_xor(ax, 32);
    ay += __shfl_xor(ay, 32);
    float ds = din_s[node];
    gxs += fmaxf(fmaf(ax, ds, bb.x), 0.f);
    gys += fmaxf(fmaf(ay, ds, bb.y), 0.f);
  }
  if (half == 0){
    atomicAdd(&bs[2 * l], gxs);
    atomicAdd(&bs[2 * l + 1], gys);
  }
  __syncthreads();
  if (tid < 64) atomicAdd(&sums[(size_t)g * 64 + tid], bs[tid]);
}

// ---------------- classifier (counts from gb) ----------------
__global__ __launch_bounds__(256) void k_classifier(const float* __restrict__ sums, const int* __restrict__ gb,
    const float* __restrict__ Wc1, const float* __restrict__ bc1,
    const float* __restrict__ Wc2, const float* __restrict__ bc2,
    const float* __restrict__ Wc3, const float* __restrict__ bc3,
    const float* __restrict__ Wc4, const float* __restrict__ bc4,
    float* __restrict__ out){
  __shared__ float w1[64 * 18], w2[18 * 12], w3[12 * 6], w4[6 * 2];
  __shared__ float B1[18], B2[12], B3[6], B4[2];
  int tid = threadIdx.x;
  for (int i = tid; i < 64 * 18; i += 256) w1[i] = Wc1[i];
  for (int i = tid; i < 18 * 12; i += 256) w2[i] = Wc2[i];
  for (int i = tid; i < 12 * 6;  i += 256) w3[i] = Wc3[i];
  for (int i = tid; i < 6 * 2;   i += 256) w4[i] = Wc4[i];
  if (tid < 18) B1[tid] = bc1[tid];
  if (tid < 12) B2[tid] = bc2[tid];
  if (tid < 6)  B3[tid] = bc3[tid];
  if (tid < 2)  B4[tid] = bc4[tid];
  __syncthreads();
  int g = blockIdx.x * 256 + tid;
  float cnt = fmaxf((float)(gb[g + 1] - gb[g]), 1.0f);
  float h[64];
#pragma unroll
  for (int f = 0; f < 64; ++f) h[f] = sums[(size_t)g * 64 + f] / cnt;
  float t1[18];
#pragma unroll
  for (int j = 0; j < 18; ++j){
    float s = B1[j];
    for (int f = 0; f < 64; ++f) s = fmaf(h[f], w1[f * 18 + j], s);
    t1[j] = s;
  }
  float t2[12];
#pragma unroll
  for (int j = 0; j < 12; ++j){
    float s = B2[j];
    for (int f = 0; f < 18; ++f) s = fmaf(t1[f], w2[f * 12 + j], s);
    t2[j] = s;
  }
  float t3[6];
#pragma unroll
  for (int j = 0; j < 6; ++j){
    float s = B3[j];
    for (int f = 0; f < 12; ++f) s = fmaf(t2[f], w3[f * 6 + j], s);
    t3[j] = s;
  }
#pragma unroll
  for (int j = 0; j < 2; ++j){
    float s = B4[j];
    for (int f = 0; f < 6; ++f) s = fmaf(t3[f], w4[f * 2 + j], s);
    out[(size_t)g * 2 + j] = s;
  }
}

extern "C" void kernel_launch(void* const* d_in, const int* in_sizes, int n_in,
                              void* d_out, int out_size, void* d_ws, size_t ws_size,
                              hipStream_t stream){
  const float* x   = (const float*)d_in[0];
  const int*   src = (const int*)d_in[1];
  const int*   dst = (const int*)d_in[2];
  const int*   gid = (const int*)d_in[3];
  const float* W1  = (const float*)d_in[4];
  const float* b1  = (const float*)d_in[5];
  const float* W2  = (const float*)d_in[6];
  const float* b2  = (const float*)d_in[7];
  const float* Wc1 = (const float*)d_in[8];
  const float* bc1 = (const float*)d_in[9];
  const float* Wc2 = (const float*)d_in[10];
  const float* bc2 = (const float*)d_in[11];
  const float* Wc3 = (const float*)d_in[12];
  const float* bc3 = (const float*)d_in[13];
  const float* Wc4 = (const float*)d_in[14];
  const float* bc4 = (const float*)d_in[15];
  float* out = (float*)d_out;

  const int n_nodes = in_sizes[3];
  const int n_edges = in_sizes[1];
  const int F1 = 256, F2 = 64;
  const int NB   = (n_nodes + 511) >> 9;
  const int NBLK = (n_edges + 4095) / 4096;

  char* w = (char*)d_ws;
  size_t o = 0;
  auto alloc = [&](size_t bytes) -> char* {
    char* p = w + o;
    o = align_up(o + bytes, 256);
    return p;
  };
  float* sums      = (float*)alloc((size_t)NGRAPHS * F2 * 4);
  int*   gb        = (int*)  alloc((size_t)(NGRAPHS + 1) * 4);
  int*   cntS      = (int*)  alloc((size_t)NBLK * 256 * 4);
  int*   cntD      = (int*)  alloc((size_t)NBLK * 256 * 4);
  int*   totS      = (int*)  alloc((size_t)256 * 4);
  int*   totD      = (int*)  alloc((size_t)256 * 4);
  int*   baseS     = (int*)  alloc((size_t)256 * 4);
  int*   baseD     = (int*)  alloc((size_t)256 * 4);
  float* dout_s    = (float*)alloc((size_t)n_nodes * 4);
  float* din_s     = (float*)alloc((size_t)n_nodes * 4);
  int*   offs      = (int*)  alloc((size_t)(n_nodes + 1) * 4);
  int*   csr_src   = (int*)  alloc((size_t)n_edges * 4);
  unsigned short* Wt1 = (unsigned short*)alloc((size_t)256 * 128 * 2);
  unsigned short* Wt2 = (unsigned short*)alloc((size_t)64 * 256 * 2);
  unsigned int*   xb  = (unsigned int*)  alloc((size_t)n_nodes * 128 * 2);
  unsigned short* aggb= (unsigned short*)alloc((size_t)n_nodes * 128 * 2);
  unsigned short* h1b = (unsigned short*)alloc((size_t)n_nodes * F1 * 2);
  // aliases inside aggb region (consumed before spmm1 writes aggb)
  int2*  pairD = (int2*)aggb;
  int*   srcS  = (int*)((char*)aggb + (size_t)n_edges * 8);
  // t2 lives in the (otherwise unused) h1b buffer — NOT aggb, which k_gemm12 reads as A.
  unsigned short* t2b = h1b;

  hipMemsetAsync(sums, 0, (size_t)NGRAPHS * F2 * 4, stream);

  // deterministic radix partition + fused CSR build; misc prep rides on partcount's grid
  {
    long long miscTotal = 128 * 256 + 256 * 64 + n_nodes;
    int miscBlocks = (int)((miscTotal + 255) / 256);
    k_partcount<<<NBLK + miscBlocks, 256, 0, stream>>>(src, dst, cntS, cntD, n_edges, NBLK,
                                                       W1, Wt1, W2, Wt2, gid, gb, n_nodes);
  }
  k_colscan     <<<2 * NB, 256, 0, stream>>>(cntS, cntD, totS, totD, NBLK, NB);
  k_scatter_det <<<NBLK, 256, 0, stream>>>(src, dst, cntS, cntD, totS, totD, baseS, baseD, pairD, srcS, n_edges, NB);
  k_bucket_build<<<2 * NB, 256, 0, stream>>>(pairD, baseD, srcS, baseS, offs, din_s, dout_s, csr_src,
                                             NB, n_nodes, n_edges);

  // x -> bf16 prescaled by dout^-1/2 (full grid)
  {
    long long total4 = (long long)n_nodes * 32;
    k_prep2<<<(int)((total4 + 255) / 256), 256, 0, stream>>>(x, dout_s, xb, total4);
  }

  int gx = (n_nodes + 127) / 128;
  // layer 1 spmm, then fused GEMM1+GEMM2 (h1 never hits global memory)
  {
    long long threads = (long long)n_nodes * 64;
    k_spmm1<<<(int)((threads + 255) / 256), 256, 0, stream>>>(xb, offs, csr_src, (unsigned int*)aggb, n_nodes);
    k_gemm12<<<gx, 256, 0, stream>>>(aggb, Wt1, Wt2, t2b, n_nodes, din_s, dout_s, b1);
  }
  // layer 2 spmm + per-graph mean-pool
  k_spmm2_fused<<<NGRAPHS * SCHUNK, 256, 0, stream>>>(t2b, offs, csr_src, din_s, b2, gb, sums);
  // classifier
  k_classifier<<<NGRAPHS / 256, 256, 0, stream>>>(sums, gb, Wc1, bc1, Wc2, bc2, Wc3, bc3, Wc4, bc4, out);
}